// Round 1
// baseline (2556.372 us; speedup 1.0000x reference)
//
#include <hip/hip_runtime.h>
#include <hip/hip_bf16.h>
#include <math.h>

// GIN 2-layer: aggr = segment_sum(h[src], dst); (h+aggr)@W + b; relu; layer2; log_softmax.
// Layer-2 reordered: (h1+aggr2)@W2+b2 = t + segment_sum(t[src]) + b2 with t = h1@W2,
// so the scatter is over 40 feats instead of 128.

#define IN_DIM 64
#define HID_DIM 128
#define OUT_DIM 40

// ---------------- scatter-add kernels (atomic, float4 gather) ----------------

__global__ __launch_bounds__(256) void scatter_add_64(
    const float4* __restrict__ x4, const int* __restrict__ src,
    const int* __restrict__ dst, float* __restrict__ aggr, int n_edges) {
  int idx = blockIdx.x * 256 + threadIdx.x;
  int total = n_edges * 16;                // 16 float4 groups per edge (64 floats)
  if (idx >= total) return;
  int e = idx >> 4, g = idx & 15;
  int s = src[e], d = dst[e];
  float4 v = x4[(size_t)s * 16 + g];
  float* out = aggr + (size_t)d * 64 + g * 4;
  atomicAdd(out + 0, v.x);
  atomicAdd(out + 1, v.y);
  atomicAdd(out + 2, v.z);
  atomicAdd(out + 3, v.w);
}

__global__ __launch_bounds__(256) void scatter_add_40(
    const float4* __restrict__ t4, const int* __restrict__ src,
    const int* __restrict__ dst, float* __restrict__ aggr, int n_edges) {
  int idx = blockIdx.x * 256 + threadIdx.x;
  int total = n_edges * 10;                // 10 float4 groups per edge (40 floats)
  if (idx >= total) return;
  int e = idx / 10, g = idx - e * 10;
  int s = src[e], d = dst[e];
  float4 v = t4[(size_t)s * 10 + g];
  float* out = aggr + (size_t)d * 40 + g * 4;
  atomicAdd(out + 0, v.x);
  atomicAdd(out + 1, v.y);
  atomicAdd(out + 2, v.z);
  atomicAdd(out + 3, v.w);
}

// ---------------- layer 1: h1 = relu((x + aggr1) @ W1 + b1) ----------------

#define NB1 32
__global__ __launch_bounds__(256) void gemm1_relu(
    const float* __restrict__ x, const float* __restrict__ aggr,
    const float* __restrict__ W1, const float* __restrict__ b1,
    float* __restrict__ h1, int n_nodes) {
  __shared__ float Ws[IN_DIM * HID_DIM];   // 32 KB
  __shared__ float bs[HID_DIM];
  __shared__ float ins[NB1 * IN_DIM];      // 8 KB
  int tid = threadIdx.x;
  for (int i = tid; i < IN_DIM * HID_DIM; i += 256) Ws[i] = W1[i];
  if (tid < HID_DIM) bs[tid] = b1[tid];
  int n0 = blockIdx.x * NB1;
  for (int i = tid; i < NB1 * IN_DIM; i += 256) {
    int n = n0 + (i >> 6), k = i & 63;
    ins[i] = (n < n_nodes) ? x[(size_t)n * IN_DIM + k] + aggr[(size_t)n * IN_DIM + k] : 0.f;
  }
  __syncthreads();
  for (int o = tid; o < NB1 * HID_DIM; o += 256) {
    int nl = o >> 7, j = o & 127;
    int n = n0 + nl;
    if (n >= n_nodes) continue;
    float acc = bs[j];
    const float* in = &ins[nl * IN_DIM];
#pragma unroll
    for (int k = 0; k < IN_DIM; ++k) acc = fmaf(in[k], Ws[k * HID_DIM + j], acc);
    h1[(size_t)n * HID_DIM + j] = fmaxf(acc, 0.f);
  }
}

// ---------------- layer 2 matmul (no bias): t = h1 @ W2 ----------------

#define NB2 32
__global__ __launch_bounds__(256) void gemm2(
    const float* __restrict__ h1, const float* __restrict__ W2,
    float* __restrict__ t, int n_nodes) {
  __shared__ float Ws[HID_DIM * OUT_DIM];  // 20 KB
  __shared__ float ins[NB2 * HID_DIM];     // 16 KB
  int tid = threadIdx.x;
  for (int i = tid; i < HID_DIM * OUT_DIM; i += 256) Ws[i] = W2[i];
  int n0 = blockIdx.x * NB2;
  for (int i = tid; i < NB2 * HID_DIM; i += 256) {
    int n = n0 + (i >> 7), k = i & 127;
    ins[i] = (n < n_nodes) ? h1[(size_t)n * HID_DIM + k] : 0.f;
  }
  __syncthreads();
  for (int o = tid; o < NB2 * OUT_DIM; o += 256) {
    int nl = o / OUT_DIM, j = o - nl * OUT_DIM;
    int n = n0 + nl;
    if (n >= n_nodes) continue;
    float acc = 0.f;
    const float* in = &ins[nl * HID_DIM];
#pragma unroll
    for (int k = 0; k < HID_DIM; ++k) acc = fmaf(in[k], Ws[k * OUT_DIM + j], acc);
    t[(size_t)n * OUT_DIM + j] = acc;
  }
}

// ------- final: out = log_softmax(t + aggrT + b2), one wave per node -------

__global__ __launch_bounds__(256) void final_lsm(
    const float* __restrict__ t, const float* __restrict__ aggrT,
    const float* __restrict__ b2, float* __restrict__ out, int n_nodes) {
  int gtid = blockIdx.x * 256 + threadIdx.x;
  int node = gtid >> 6;
  int lane = threadIdx.x & 63;
  if (node >= n_nodes) return;
  float z = -INFINITY;
  if (lane < OUT_DIM)
    z = t[(size_t)node * OUT_DIM + lane] + aggrT[(size_t)node * OUT_DIM + lane] + b2[lane];
  float m = z;
#pragma unroll
  for (int off = 32; off; off >>= 1) m = fmaxf(m, __shfl_xor(m, off, 64));
  float e = (lane < OUT_DIM) ? expf(z - m) : 0.f;
  float s = e;
#pragma unroll
  for (int off = 32; off; off >>= 1) s += __shfl_xor(s, off, 64);
  if (lane < OUT_DIM) out[(size_t)node * OUT_DIM + lane] = z - m - logf(s);
}

// ---------------- launch ----------------

extern "C" void kernel_launch(void* const* d_in, const int* in_sizes, int n_in,
                              void* d_out, int out_size, void* d_ws, size_t ws_size,
                              hipStream_t stream) {
  const float* x  = (const float*)d_in[0];
  const int*   ei = (const int*)d_in[1];       // [2][E], int32 (JAX x64-disabled)
  const float* W1 = (const float*)d_in[2];
  const float* b1 = (const float*)d_in[3];
  const float* W2 = (const float*)d_in[4];
  const float* b2 = (const float*)d_in[5];
  float* out = (float*)d_out;

  int n_nodes = in_sizes[0] / IN_DIM;
  int n_edges = in_sizes[1] / 2;
  const int* src = ei;
  const int* dst = ei + n_edges;

  float* ws    = (float*)d_ws;
  float* aggr1 = ws;                                   // n_nodes*64
  float* h1    = aggr1 + (size_t)n_nodes * IN_DIM;     // n_nodes*128
  float* t     = h1 + (size_t)n_nodes * HID_DIM;       // n_nodes*40
  float* aggrT = t + (size_t)n_nodes * OUT_DIM;        // n_nodes*40

  hipMemsetAsync(aggr1, 0, (size_t)n_nodes * IN_DIM * sizeof(float), stream);
  hipMemsetAsync(aggrT, 0, (size_t)n_nodes * OUT_DIM * sizeof(float), stream);

  {
    int total = n_edges * 16;
    scatter_add_64<<<(total + 255) / 256, 256, 0, stream>>>(
        (const float4*)x, src, dst, aggr1, n_edges);
  }
  {
    int grid = (n_nodes + NB1 - 1) / NB1;
    gemm1_relu<<<grid, 256, 0, stream>>>(x, aggr1, W1, b1, h1, n_nodes);
  }
  {
    int grid = (n_nodes + NB2 - 1) / NB2;
    gemm2<<<grid, 256, 0, stream>>>(h1, W2, t, n_nodes);
  }
  {
    int total = n_edges * 10;
    scatter_add_40<<<(total + 255) / 256, 256, 0, stream>>>(
        (const float4*)t, src, dst, aggrT, n_edges);
  }
  {
    int total = n_nodes * 64;
    final_lsm<<<(total + 255) / 256, 256, 0, stream>>>(t, aggrT, b2, out, n_nodes);
  }
}

// Round 2
// 737.876 us; speedup vs baseline: 3.4645x; 3.4645x over previous
//
#include <hip/hip_runtime.h>
#include <hip/hip_bf16.h>
#include <math.h>

// GIN 2-layer. Round 2: replace fp32 atomic scatters (1.6GB HBM write-through)
// with device-built CSR + gather.
//   CSR build: count (int atomics) -> exclusive scan -> cursor fill
//   layer1: per-node wave gathers x[src] rows, fused with GEMM1+bias+relu
//   layer2: t = h1 @ W2 ; out = log_softmax(t[n] + sum_j t[j] + b2)  (gather)

#define IN_DIM 64
#define HID_DIM 128
#define OUT_DIM 40

// ---------------- CSR build ----------------

__global__ __launch_bounds__(256) void count_deg(const int* __restrict__ dst,
                                                 int* __restrict__ deg, int n_edges) {
  int e = blockIdx.x * 256 + threadIdx.x;
  if (e < n_edges) atomicAdd(&deg[dst[e]], 1);
}

// blocks of 1024 elems, 256 threads x 4 elems
__global__ __launch_bounds__(256) void scan1(const int* __restrict__ deg, int* __restrict__ off,
                                             int* __restrict__ bsums, int n) {
  __shared__ int wsum[4];
  int base = blockIdx.x * 1024;
  int tid = threadIdx.x;
  int lane = tid & 63, wave = tid >> 6;
  int i0 = base + tid * 4;
  int v0 = (i0 + 0 < n) ? deg[i0 + 0] : 0;
  int v1 = (i0 + 1 < n) ? deg[i0 + 1] : 0;
  int v2 = (i0 + 2 < n) ? deg[i0 + 2] : 0;
  int v3 = (i0 + 3 < n) ? deg[i0 + 3] : 0;
  int S = v0 + v1 + v2 + v3;
  int incl = S;
#pragma unroll
  for (int d = 1; d < 64; d <<= 1) {
    int t = __shfl_up(incl, d, 64);
    if (lane >= d) incl += t;
  }
  if (lane == 63) wsum[wave] = incl;
  __syncthreads();
  int wpre = 0;
  for (int w = 0; w < wave; ++w) wpre += wsum[w];
  int excl = wpre + incl - S;
  if (i0 + 0 < n) off[i0 + 0] = excl;
  if (i0 + 1 < n) off[i0 + 1] = excl + v0;
  if (i0 + 2 < n) off[i0 + 2] = excl + v0 + v1;
  if (i0 + 3 < n) off[i0 + 3] = excl + v0 + v1 + v2;
  if (tid == 255) bsums[blockIdx.x] = wpre + incl;
}

__global__ void scan2(int* bsums, int nb) {
  if (threadIdx.x == 0 && blockIdx.x == 0) {
    int run = 0;
    for (int i = 0; i < nb; ++i) { int v = bsums[i]; bsums[i] = run; run += v; }
  }
}

__global__ __launch_bounds__(256) void scan3(int* __restrict__ off, const int* __restrict__ boff,
                                             int n, int n_edges) {
  int i = blockIdx.x * 256 + threadIdx.x;
  if (i < n) off[i] += boff[i >> 10];
  if (i == n) off[n] = n_edges;
}

__global__ __launch_bounds__(256) void fill_csr(const int* __restrict__ src,
                                                const int* __restrict__ dst,
                                                int* __restrict__ cursor,
                                                int* __restrict__ esrc, int n_edges) {
  int e = blockIdx.x * 256 + threadIdx.x;
  if (e >= n_edges) return;
  int p = atomicAdd(&cursor[dst[e]], 1);
  esrc[p] = src[e];
}

// ------- layer 1 fused: h1 = relu((x[n] + sum_j x[j]) @ W1 + b1) -------

#define L1_NODES 16
__global__ __launch_bounds__(256) void layer1_fused(
    const float* __restrict__ x, const int* __restrict__ off, const int* __restrict__ esrc,
    const float* __restrict__ W1, const float* __restrict__ b1,
    float* __restrict__ h1, int n_nodes) {
  __shared__ float Ws[IN_DIM * HID_DIM];   // 32 KB
  __shared__ float bs[HID_DIM];
  __shared__ float s1[L1_NODES][IN_DIM];   // 4 KB
  int tid = threadIdx.x;
  for (int i = tid; i < IN_DIM * HID_DIM; i += 256) Ws[i] = W1[i];
  if (tid < HID_DIM) bs[tid] = b1[tid];
  int n0 = blockIdx.x * L1_NODES;
  int wave = tid >> 6, lane = tid & 63;
  for (int nl = wave; nl < L1_NODES; nl += 4) {
    int n = n0 + nl;
    if (n < n_nodes) {
      float acc = x[(size_t)n * IN_DIM + lane];
      int e0 = off[n], e1 = off[n + 1];
      for (int e = e0; e < e1; ++e) {
        int s = esrc[e];
        acc += x[(size_t)s * IN_DIM + lane];
      }
      s1[nl][lane] = acc;
    }
  }
  __syncthreads();
  for (int o = tid; o < L1_NODES * HID_DIM; o += 256) {
    int nl = o >> 7, j = o & 127;
    int n = n0 + nl;
    if (n >= n_nodes) continue;
    float acc = bs[j];
    const float* in = s1[nl];
#pragma unroll
    for (int k = 0; k < IN_DIM; ++k) acc = fmaf(in[k], Ws[k * HID_DIM + j], acc);
    h1[(size_t)n * HID_DIM + j] = fmaxf(acc, 0.f);
  }
}

// ---------------- t = h1 @ W2 (no bias) ----------------

#define NB2 32
__global__ __launch_bounds__(256) void gemm2(
    const float* __restrict__ h1, const float* __restrict__ W2,
    float* __restrict__ t, int n_nodes) {
  __shared__ float Ws[HID_DIM * OUT_DIM];  // 20 KB
  __shared__ float ins[NB2 * HID_DIM];     // 16 KB
  int tid = threadIdx.x;
  for (int i = tid; i < HID_DIM * OUT_DIM; i += 256) Ws[i] = W2[i];
  int n0 = blockIdx.x * NB2;
  for (int i = tid; i < NB2 * HID_DIM; i += 256) {
    int n = n0 + (i >> 7), k = i & 127;
    ins[i] = (n < n_nodes) ? h1[(size_t)n * HID_DIM + k] : 0.f;
  }
  __syncthreads();
  for (int o = tid; o < NB2 * OUT_DIM; o += 256) {
    int nl = o / OUT_DIM, j = o - nl * OUT_DIM;
    int n = n0 + nl;
    if (n >= n_nodes) continue;
    float acc = 0.f;
    const float* in = &ins[nl * HID_DIM];
#pragma unroll
    for (int k = 0; k < HID_DIM; ++k) acc = fmaf(in[k], Ws[k * OUT_DIM + j], acc);
    t[(size_t)n * OUT_DIM + j] = acc;
  }
}

// ------- final: out = log_softmax(t[n] + sum_j t[j] + b2), one wave/node -------

__global__ __launch_bounds__(256) void final_fused(
    const float* __restrict__ t, const int* __restrict__ off, const int* __restrict__ esrc,
    const float* __restrict__ b2, float* __restrict__ out, int n_nodes) {
  int node = blockIdx.x * 4 + (threadIdx.x >> 6);
  int lane = threadIdx.x & 63;
  if (node >= n_nodes) return;
  // t is padded by 64 floats so unguarded lane reads (lane 40..63) stay in-bounds
  float z = t[(size_t)node * OUT_DIM + lane] + ((lane < OUT_DIM) ? b2[lane] : 0.f);
  int e0 = off[node], e1 = off[node + 1];
  for (int e = e0; e < e1; ++e) {
    int s = esrc[e];
    z += t[(size_t)s * OUT_DIM + lane];
  }
  float zz = (lane < OUT_DIM) ? z : -INFINITY;
  float m = zz;
#pragma unroll
  for (int d = 32; d; d >>= 1) m = fmaxf(m, __shfl_xor(m, d, 64));
  float e = (lane < OUT_DIM) ? expf(zz - m) : 0.f;
  float s = e;
#pragma unroll
  for (int d = 32; d; d >>= 1) s += __shfl_xor(s, d, 64);
  if (lane < OUT_DIM) out[(size_t)node * OUT_DIM + lane] = zz - m - logf(s);
}

// ---------------- launch ----------------

extern "C" void kernel_launch(void* const* d_in, const int* in_sizes, int n_in,
                              void* d_out, int out_size, void* d_ws, size_t ws_size,
                              hipStream_t stream) {
  const float* x  = (const float*)d_in[0];
  const int*   ei = (const int*)d_in[1];       // [2][E] int32
  const float* W1 = (const float*)d_in[2];
  const float* b1 = (const float*)d_in[3];
  const float* W2 = (const float*)d_in[4];
  const float* b2 = (const float*)d_in[5];
  float* out = (float*)d_out;

  int n_nodes = in_sizes[0] / IN_DIM;
  int n_edges = in_sizes[1] / 2;
  const int* src = ei;
  const int* dst = ei + n_edges;

  // workspace layout
  char* p = (char*)d_ws;
  int* deg    = (int*)p;            p += (size_t)n_nodes * 4;
  int* off    = (int*)p;            p += (size_t)(n_nodes + 1) * 4;
  int* cursor = (int*)p;            p += (size_t)n_nodes * 4;
  int* bsums  = (int*)p;            p += 1024;
  int* esrc   = (int*)p;            p += (size_t)n_edges * 4;
  float* h1   = (float*)p;          p += (size_t)n_nodes * HID_DIM * 4;
  float* t    = (float*)p;          p += ((size_t)n_nodes * OUT_DIM + 64) * 4;

  hipMemsetAsync(deg, 0, (size_t)n_nodes * 4, stream);

  int egrid = (n_edges + 255) / 256;
  count_deg<<<egrid, 256, 0, stream>>>(dst, deg, n_edges);

  int nb = (n_nodes + 1023) / 1024;
  scan1<<<nb, 256, 0, stream>>>(deg, off, bsums, n_nodes);
  scan2<<<1, 64, 0, stream>>>(bsums, nb);
  scan3<<<(n_nodes + 256) / 256, 256, 0, stream>>>(off, bsums, n_nodes, n_edges);

  hipMemcpyAsync(cursor, off, (size_t)n_nodes * 4, hipMemcpyDeviceToDevice, stream);
  fill_csr<<<egrid, 256, 0, stream>>>(src, dst, cursor, esrc, n_edges);

  layer1_fused<<<(n_nodes + L1_NODES - 1) / L1_NODES, 256, 0, stream>>>(
      x, off, esrc, W1, b1, h1, n_nodes);
  gemm2<<<(n_nodes + NB2 - 1) / NB2, 256, 0, stream>>>(h1, W2, t, n_nodes);
  final_fused<<<(n_nodes + 3) / 4, 256, 0, stream>>>(t, off, esrc, b2, out, n_nodes);
}

// Round 3
// 446.493 us; speedup vs baseline: 5.7255x; 1.6526x over previous
//
#include <hip/hip_runtime.h>
#include <hip/hip_bf16.h>
#include <math.h>

// GIN 2-layer, round 3.
//  CSR build (count -> scan -> fill), then:
//  agg1:   aggr1[n] = x[n] + sum_{j in N(n)} x[j]     (unroll-4 gather, no LDS)
//  gemm1:  h1 = relu(aggr1 @ W1 + b1)                  (register-tiled, 64 nodes/blk)
//  gemm2:  t = h1 @ W2                                 (register-tiled)
//  final:  out = log_softmax(t[n] + sum t[j] + b2)     (unroll-4 gather + wave softmax)

#define IN_DIM 64
#define HID_DIM 128
#define OUT_DIM 40

// ---------------- CSR build ----------------

__global__ __launch_bounds__(256) void count_deg(const int* __restrict__ dst,
                                                 int* __restrict__ deg, int n_edges) {
  int e = blockIdx.x * 256 + threadIdx.x;
  if (e < n_edges) atomicAdd(&deg[dst[e]], 1);
}

__global__ __launch_bounds__(256) void scan1(const int* __restrict__ deg, int* __restrict__ off,
                                             int* __restrict__ bsums, int n) {
  __shared__ int wsum[4];
  int base = blockIdx.x * 1024;
  int tid = threadIdx.x;
  int lane = tid & 63, wave = tid >> 6;
  int i0 = base + tid * 4;
  int v0 = (i0 + 0 < n) ? deg[i0 + 0] : 0;
  int v1 = (i0 + 1 < n) ? deg[i0 + 1] : 0;
  int v2 = (i0 + 2 < n) ? deg[i0 + 2] : 0;
  int v3 = (i0 + 3 < n) ? deg[i0 + 3] : 0;
  int S = v0 + v1 + v2 + v3;
  int incl = S;
#pragma unroll
  for (int d = 1; d < 64; d <<= 1) {
    int t = __shfl_up(incl, d, 64);
    if (lane >= d) incl += t;
  }
  if (lane == 63) wsum[wave] = incl;
  __syncthreads();
  int wpre = 0;
  for (int w = 0; w < wave; ++w) wpre += wsum[w];
  int excl = wpre + incl - S;
  if (i0 + 0 < n) off[i0 + 0] = excl;
  if (i0 + 1 < n) off[i0 + 1] = excl + v0;
  if (i0 + 2 < n) off[i0 + 2] = excl + v0 + v1;
  if (i0 + 3 < n) off[i0 + 3] = excl + v0 + v1 + v2;
  if (tid == 255) bsums[blockIdx.x] = wpre + incl;
}

__global__ void scan2(int* bsums, int nb) {
  if (threadIdx.x == 0 && blockIdx.x == 0) {
    int run = 0;
    for (int i = 0; i < nb; ++i) { int v = bsums[i]; bsums[i] = run; run += v; }
  }
}

__global__ __launch_bounds__(256) void scan3(int* __restrict__ off, const int* __restrict__ boff,
                                             int n, int n_edges) {
  int i = blockIdx.x * 256 + threadIdx.x;
  if (i < n) off[i] += boff[i >> 10];
  if (i == n) off[n] = n_edges;
}

__global__ __launch_bounds__(256) void fill_csr(const int* __restrict__ src,
                                                const int* __restrict__ dst,
                                                int* __restrict__ cursor,
                                                int* __restrict__ esrc, int n_edges) {
  int e = blockIdx.x * 256 + threadIdx.x;
  if (e >= n_edges) return;
  int p = atomicAdd(&cursor[dst[e]], 1);
  esrc[p] = src[e];
}

// ---------------- aggregation: aggr1 = x + gather-sum ----------------

__global__ __launch_bounds__(256) void agg1(
    const float* __restrict__ x, const int* __restrict__ off, const int* __restrict__ esrc,
    float* __restrict__ aggr, int n_nodes) {
  int node = blockIdx.x * 4 + (threadIdx.x >> 6);
  int lane = threadIdx.x & 63;
  if (node >= n_nodes) return;
  float a0 = x[(size_t)node * IN_DIM + lane];
  float a1 = 0.f, a2 = 0.f, a3 = 0.f;
  int e = off[node], e1 = off[node + 1];
  for (; e + 4 <= e1; e += 4) {
    int s0 = esrc[e + 0], s1 = esrc[e + 1], s2 = esrc[e + 2], s3 = esrc[e + 3];
    a0 += x[(size_t)s0 * IN_DIM + lane];
    a1 += x[(size_t)s1 * IN_DIM + lane];
    a2 += x[(size_t)s2 * IN_DIM + lane];
    a3 += x[(size_t)s3 * IN_DIM + lane];
  }
  for (; e < e1; ++e) a1 += x[(size_t)esrc[e] * IN_DIM + lane];
  aggr[(size_t)node * IN_DIM + lane] = (a0 + a1) + (a2 + a3);
}

// ------- gemm1: h1 = relu(aggr1 @ W1 + b1), 64 nodes/block, reg-tiled -------

#define G1_NODES 64
__global__ __launch_bounds__(256) void gemm1_relu(
    const float* __restrict__ aggr, const float* __restrict__ W1,
    const float* __restrict__ b1, float* __restrict__ h1, int n_nodes) {
  __shared__ float Ws[IN_DIM * HID_DIM];   // [k][j], 32 KB
  __shared__ float insT[IN_DIM * 68];      // [k][nl], stride 68 (float4-aligned), 17.4 KB
  int tid = threadIdx.x;
  int n0 = blockIdx.x * G1_NODES;
  for (int i = tid; i < IN_DIM * HID_DIM; i += 256) Ws[i] = W1[i];
  {
    int lane = tid & 63, w = tid >> 6;
    for (int nl = w; nl < G1_NODES; nl += 4) {
      int n = n0 + nl;
      insT[lane * 68 + nl] = (n < n_nodes) ? aggr[(size_t)n * IN_DIM + lane] : 0.f;
    }
  }
  __syncthreads();
  int jb = tid & 31;      // j0 = jb*4
  int nlb = tid >> 5;     // nl = nlb*8 + i
  float4 bias = ((const float4*)b1)[jb];
  float acc[8][4];
#pragma unroll
  for (int i = 0; i < 8; ++i) {
    acc[i][0] = bias.x; acc[i][1] = bias.y; acc[i][2] = bias.z; acc[i][3] = bias.w;
  }
  const float4* WsV = (const float4*)Ws;
  const float4* inV = (const float4*)insT;
#pragma unroll 4
  for (int k = 0; k < IN_DIM; ++k) {
    float4 w = WsV[k * 32 + jb];
    float4 aA = inV[k * 17 + nlb * 2 + 0];
    float4 aB = inV[k * 17 + nlb * 2 + 1];
    float av[8] = {aA.x, aA.y, aA.z, aA.w, aB.x, aB.y, aB.z, aB.w};
#pragma unroll
    for (int i = 0; i < 8; ++i) {
      acc[i][0] = fmaf(av[i], w.x, acc[i][0]);
      acc[i][1] = fmaf(av[i], w.y, acc[i][1]);
      acc[i][2] = fmaf(av[i], w.z, acc[i][2]);
      acc[i][3] = fmaf(av[i], w.w, acc[i][3]);
    }
  }
#pragma unroll
  for (int i = 0; i < 8; ++i) {
    int n = n0 + nlb * 8 + i;
    if (n >= n_nodes) continue;
    float4 o;
    o.x = fmaxf(acc[i][0], 0.f); o.y = fmaxf(acc[i][1], 0.f);
    o.z = fmaxf(acc[i][2], 0.f); o.w = fmaxf(acc[i][3], 0.f);
    *(float4*)&h1[(size_t)n * HID_DIM + jb * 4] = o;
  }
}

// ------- gemm2: t = h1 @ W2 (N=40 padded to 48), 64 nodes/block -------

#define G2_NODES 64
__global__ __launch_bounds__(256) void gemm2(
    const float* __restrict__ h1, const float* __restrict__ W2,
    float* __restrict__ t, int n_nodes) {
  __shared__ float W2s[HID_DIM * 48];    // [k][j] padded, 24.6 KB
  __shared__ float insT[HID_DIM * 68];   // [k][nl], 34.8 KB
  int tid = threadIdx.x;
  int n0 = blockIdx.x * G2_NODES;
  for (int i = tid; i < HID_DIM * 48; i += 256) {
    int k = i / 48, j = i - k * 48;
    W2s[i] = (j < OUT_DIM) ? W2[k * OUT_DIM + j] : 0.f;
  }
  {
    int lane = tid & 63, w = tid >> 6;
    for (int nl = w; nl < G2_NODES; nl += 4) {
      int n = n0 + nl;
      float v0 = 0.f, v1 = 0.f;
      if (n < n_nodes) {
        v0 = h1[(size_t)n * HID_DIM + lane];
        v1 = h1[(size_t)n * HID_DIM + 64 + lane];
      }
      insT[lane * 68 + nl] = v0;
      insT[(64 + lane) * 68 + nl] = v1;
    }
  }
  __syncthreads();
  if (tid >= 192) return;
  int jb = tid % 12;    // j0 = jb*4 (jb 10,11 are padding)
  int nlb = tid / 12;   // 0..15, nl = nlb*4 + i
  float acc[4][4] = {};
  const float4* WsV = (const float4*)W2s;
  const float4* inV = (const float4*)insT;
#pragma unroll 4
  for (int k = 0; k < HID_DIM; ++k) {
    float4 w = WsV[k * 12 + jb];
    float4 a = inV[k * 17 + nlb];
    float av[4] = {a.x, a.y, a.z, a.w};
#pragma unroll
    for (int i = 0; i < 4; ++i) {
      acc[i][0] = fmaf(av[i], w.x, acc[i][0]);
      acc[i][1] = fmaf(av[i], w.y, acc[i][1]);
      acc[i][2] = fmaf(av[i], w.z, acc[i][2]);
      acc[i][3] = fmaf(av[i], w.w, acc[i][3]);
    }
  }
  if (jb < 10) {
#pragma unroll
    for (int i = 0; i < 4; ++i) {
      int n = n0 + nlb * 4 + i;
      if (n >= n_nodes) continue;
      float4 o = {acc[i][0], acc[i][1], acc[i][2], acc[i][3]};
      *(float4*)&t[(size_t)n * OUT_DIM + jb * 4] = o;
    }
  }
}

// ------- final: out = log_softmax(t[n] + sum_j t[j] + b2), one wave/node -------

__global__ __launch_bounds__(256) void final_fused(
    const float* __restrict__ t, const int* __restrict__ off, const int* __restrict__ esrc,
    const float* __restrict__ b2, float* __restrict__ out, int n_nodes) {
  int node = blockIdx.x * 4 + (threadIdx.x >> 6);
  int lane = threadIdx.x & 63;
  if (node >= n_nodes) return;
  // t has +64 float pad so lanes 40..63 stay in-bounds
  float z0 = t[(size_t)node * OUT_DIM + lane];
  float z1 = 0.f, z2 = 0.f, z3 = 0.f;
  int e = off[node], e1 = off[node + 1];
  for (; e + 4 <= e1; e += 4) {
    int s0 = esrc[e + 0], s1 = esrc[e + 1], s2 = esrc[e + 2], s3 = esrc[e + 3];
    z0 += t[(size_t)s0 * OUT_DIM + lane];
    z1 += t[(size_t)s1 * OUT_DIM + lane];
    z2 += t[(size_t)s2 * OUT_DIM + lane];
    z3 += t[(size_t)s3 * OUT_DIM + lane];
  }
  for (; e < e1; ++e) z1 += t[(size_t)esrc[e] * OUT_DIM + lane];
  float z = (z0 + z1) + (z2 + z3) + ((lane < OUT_DIM) ? b2[lane] : 0.f);
  float zz = (lane < OUT_DIM) ? z : -INFINITY;
  float m = zz;
#pragma unroll
  for (int d = 32; d; d >>= 1) m = fmaxf(m, __shfl_xor(m, d, 64));
  float ev = (lane < OUT_DIM) ? expf(zz - m) : 0.f;
  float s = ev;
#pragma unroll
  for (int d = 32; d; d >>= 1) s += __shfl_xor(s, d, 64);
  if (lane < OUT_DIM) out[(size_t)node * OUT_DIM + lane] = zz - m - logf(s);
}

// ---------------- launch ----------------

extern "C" void kernel_launch(void* const* d_in, const int* in_sizes, int n_in,
                              void* d_out, int out_size, void* d_ws, size_t ws_size,
                              hipStream_t stream) {
  const float* x  = (const float*)d_in[0];
  const int*   ei = (const int*)d_in[1];    // [2][E] int32
  const float* W1 = (const float*)d_in[2];
  const float* b1 = (const float*)d_in[3];
  const float* W2 = (const float*)d_in[4];
  const float* b2 = (const float*)d_in[5];
  float* out = (float*)d_out;

  int n_nodes = in_sizes[0] / IN_DIM;
  int n_edges = in_sizes[1] / 2;
  const int* src = ei;
  const int* dst = ei + n_edges;

  char* p = (char*)d_ws;
  int* deg    = (int*)p;            p += (size_t)n_nodes * 4;
  int* off    = (int*)p;            p += (size_t)(n_nodes + 1) * 4;
  int* cursor = (int*)p;            p += (size_t)n_nodes * 4;
  int* bsums  = (int*)p;            p += 1024;
  int* esrc   = (int*)p;            p += (size_t)n_edges * 4;
  float* aggr1 = (float*)p;         p += (size_t)n_nodes * IN_DIM * 4;
  float* h1    = (float*)p;         p += (size_t)n_nodes * HID_DIM * 4;
  float* t     = (float*)p;         p += ((size_t)n_nodes * OUT_DIM + 64) * 4;

  hipMemsetAsync(deg, 0, (size_t)n_nodes * 4, stream);

  int egrid = (n_edges + 255) / 256;
  count_deg<<<egrid, 256, 0, stream>>>(dst, deg, n_edges);

  int nb = (n_nodes + 1023) / 1024;
  scan1<<<nb, 256, 0, stream>>>(deg, off, bsums, n_nodes);
  scan2<<<1, 64, 0, stream>>>(bsums, nb);
  scan3<<<(n_nodes + 256) / 256, 256, 0, stream>>>(off, bsums, n_nodes, n_edges);

  hipMemcpyAsync(cursor, off, (size_t)n_nodes * 4, hipMemcpyDeviceToDevice, stream);
  fill_csr<<<egrid, 256, 0, stream>>>(src, dst, cursor, esrc, n_edges);

  agg1<<<(n_nodes + 3) / 4, 256, 0, stream>>>(x, off, esrc, aggr1, n_nodes);
  gemm1_relu<<<(n_nodes + G1_NODES - 1) / G1_NODES, 256, 0, stream>>>(
      aggr1, W1, b1, h1, n_nodes);
  gemm2<<<(n_nodes + G2_NODES - 1) / G2_NODES, 256, 0, stream>>>(h1, W2, t, n_nodes);
  final_fused<<<(n_nodes + 3) / 4, 256, 0, stream>>>(t, off, esrc, b2, out, n_nodes);
}

// Round 4
// 436.012 us; speedup vs baseline: 5.8631x; 1.0240x over previous
//
#include <hip/hip_runtime.h>
#include <math.h>

// GIN 2-layer, round 4: bf16 intermediates for all gathered/streamed tensors
// (accumulate fp32), unroll-8 gathers, 2-edge/thread CSR fill.

#define IN_DIM 64
#define HID_DIM 128
#define OUT_DIM 40

typedef unsigned short ushort;
typedef ushort ushort4_t __attribute__((ext_vector_type(4)));
typedef ushort ushort8_t __attribute__((ext_vector_type(8)));

__device__ __forceinline__ ushort f2bf(float f) {
  unsigned u = __float_as_uint(f);
  u += 0x7fffu + ((u >> 16) & 1u);
  return (ushort)(u >> 16);
}
__device__ __forceinline__ float bf2f(ushort h) {
  return __uint_as_float(((unsigned)h) << 16);
}

// ---------------- fp32 -> bf16 bulk convert ----------------

__global__ __launch_bounds__(256) void cvt_bf16(const float4* __restrict__ in,
                                                ushort8_t* __restrict__ out, int n8) {
  int i = blockIdx.x * 256 + threadIdx.x;
  if (i >= n8) return;
  float4 a = in[2 * i], b = in[2 * i + 1];
  ushort8_t o;
  o[0] = f2bf(a.x); o[1] = f2bf(a.y); o[2] = f2bf(a.z); o[3] = f2bf(a.w);
  o[4] = f2bf(b.x); o[5] = f2bf(b.y); o[6] = f2bf(b.z); o[7] = f2bf(b.w);
  out[i] = o;
}

// ---------------- CSR build ----------------

__global__ __launch_bounds__(256) void count_deg(const int* __restrict__ dst,
                                                 int* __restrict__ deg, int n_edges) {
  int e = blockIdx.x * 256 + threadIdx.x;
  if (e < n_edges) atomicAdd(&deg[dst[e]], 1);
}

__global__ __launch_bounds__(256) void scan1(const int* __restrict__ deg, int* __restrict__ off,
                                             int* __restrict__ bsums, int n) {
  __shared__ int wsum[4];
  int base = blockIdx.x * 1024;
  int tid = threadIdx.x;
  int lane = tid & 63, wave = tid >> 6;
  int i0 = base + tid * 4;
  int v0 = (i0 + 0 < n) ? deg[i0 + 0] : 0;
  int v1 = (i0 + 1 < n) ? deg[i0 + 1] : 0;
  int v2 = (i0 + 2 < n) ? deg[i0 + 2] : 0;
  int v3 = (i0 + 3 < n) ? deg[i0 + 3] : 0;
  int S = v0 + v1 + v2 + v3;
  int incl = S;
#pragma unroll
  for (int d = 1; d < 64; d <<= 1) {
    int t = __shfl_up(incl, d, 64);
    if (lane >= d) incl += t;
  }
  if (lane == 63) wsum[wave] = incl;
  __syncthreads();
  int wpre = 0;
  for (int w = 0; w < wave; ++w) wpre += wsum[w];
  int excl = wpre + incl - S;
  if (i0 + 0 < n) off[i0 + 0] = excl;
  if (i0 + 1 < n) off[i0 + 1] = excl + v0;
  if (i0 + 2 < n) off[i0 + 2] = excl + v0 + v1;
  if (i0 + 3 < n) off[i0 + 3] = excl + v0 + v1 + v2;
  if (tid == 255) bsums[blockIdx.x] = wpre + incl;
}

__global__ void scan2(int* bsums, int nb) {
  if (threadIdx.x == 0 && blockIdx.x == 0) {
    int run = 0;
    for (int i = 0; i < nb; ++i) { int v = bsums[i]; bsums[i] = run; run += v; }
  }
}

__global__ __launch_bounds__(256) void scan3(int* __restrict__ off, const int* __restrict__ boff,
                                             int n, int n_edges) {
  int i = blockIdx.x * 256 + threadIdx.x;
  if (i < n) off[i] += boff[i >> 10];
  if (i == n) off[n] = n_edges;
}

__global__ __launch_bounds__(256) void fill_csr(const int* __restrict__ src,
                                                const int* __restrict__ dst,
                                                int* __restrict__ cursor,
                                                int* __restrict__ esrc, int n_edges) {
  int e0 = (blockIdx.x * 256 + threadIdx.x) * 2;
  if (e0 >= n_edges) return;
  int d0 = dst[e0], s0 = src[e0];
  bool two = (e0 + 1 < n_edges);
  int d1 = two ? dst[e0 + 1] : 0, s1 = two ? src[e0 + 1] : 0;
  int p0 = atomicAdd(&cursor[d0], 1);
  int p1 = two ? atomicAdd(&cursor[d1], 1) : 0;
  esrc[p0] = s0;
  if (two) esrc[p1] = s1;
}

// -------- agg1: aggr1h[n] = bf16(x[n] + sum_j x[j]), gather bf16 rows --------

__global__ __launch_bounds__(256) void agg1(
    const ushort* __restrict__ xh, const int* __restrict__ off, const int* __restrict__ esrc,
    ushort* __restrict__ aggrh, int n_nodes) {
  int node = blockIdx.x * 4 + (threadIdx.x >> 6);
  int lane = threadIdx.x & 63;
  if (node >= n_nodes) return;
  float a0 = bf2f(xh[(size_t)node * IN_DIM + lane]);
  float a1 = 0.f, a2 = 0.f, a3 = 0.f, a4 = 0.f, a5 = 0.f, a6 = 0.f, a7 = 0.f;
  int e = off[node], e1 = off[node + 1];
  for (; e + 8 <= e1; e += 8) {
    int s0 = esrc[e + 0], s1 = esrc[e + 1], s2 = esrc[e + 2], s3 = esrc[e + 3];
    int s4 = esrc[e + 4], s5 = esrc[e + 5], s6 = esrc[e + 6], s7 = esrc[e + 7];
    a0 += bf2f(xh[(size_t)s0 * IN_DIM + lane]);
    a1 += bf2f(xh[(size_t)s1 * IN_DIM + lane]);
    a2 += bf2f(xh[(size_t)s2 * IN_DIM + lane]);
    a3 += bf2f(xh[(size_t)s3 * IN_DIM + lane]);
    a4 += bf2f(xh[(size_t)s4 * IN_DIM + lane]);
    a5 += bf2f(xh[(size_t)s5 * IN_DIM + lane]);
    a6 += bf2f(xh[(size_t)s6 * IN_DIM + lane]);
    a7 += bf2f(xh[(size_t)s7 * IN_DIM + lane]);
  }
  for (; e < e1; ++e) a1 += bf2f(xh[(size_t)esrc[e] * IN_DIM + lane]);
  float s = ((a0 + a1) + (a2 + a3)) + ((a4 + a5) + (a6 + a7));
  aggrh[(size_t)node * IN_DIM + lane] = f2bf(s);
}

// ------- gemm1: h1h = bf16(relu(aggr1 @ W1 + b1)), 64 nodes/block -------

#define G1_NODES 64
__global__ __launch_bounds__(256) void gemm1_relu(
    const ushort* __restrict__ aggrh, const float* __restrict__ W1,
    const float* __restrict__ b1, ushort* __restrict__ h1h, int n_nodes) {
  __shared__ float Ws[IN_DIM * HID_DIM];   // 32 KB
  __shared__ float insT[IN_DIM * 68];      // [k][nl], 17.4 KB
  int tid = threadIdx.x;
  int n0 = blockIdx.x * G1_NODES;
  for (int i = tid; i < IN_DIM * HID_DIM; i += 256) Ws[i] = W1[i];
  {
    int lane = tid & 63, w = tid >> 6;
    for (int nl = w; nl < G1_NODES; nl += 4) {
      int n = n0 + nl;
      insT[lane * 68 + nl] = (n < n_nodes) ? bf2f(aggrh[(size_t)n * IN_DIM + lane]) : 0.f;
    }
  }
  __syncthreads();
  int jb = tid & 31;      // j0 = jb*4
  int nlb = tid >> 5;     // nl = nlb*8 + i
  float4 bias = ((const float4*)b1)[jb];
  float acc[8][4];
#pragma unroll
  for (int i = 0; i < 8; ++i) {
    acc[i][0] = bias.x; acc[i][1] = bias.y; acc[i][2] = bias.z; acc[i][3] = bias.w;
  }
  const float4* WsV = (const float4*)Ws;
  const float4* inV = (const float4*)insT;
#pragma unroll 4
  for (int k = 0; k < IN_DIM; ++k) {
    float4 w = WsV[k * 32 + jb];
    float4 aA = inV[k * 17 + nlb * 2 + 0];
    float4 aB = inV[k * 17 + nlb * 2 + 1];
    float av[8] = {aA.x, aA.y, aA.z, aA.w, aB.x, aB.y, aB.z, aB.w};
#pragma unroll
    for (int i = 0; i < 8; ++i) {
      acc[i][0] = fmaf(av[i], w.x, acc[i][0]);
      acc[i][1] = fmaf(av[i], w.y, acc[i][1]);
      acc[i][2] = fmaf(av[i], w.z, acc[i][2]);
      acc[i][3] = fmaf(av[i], w.w, acc[i][3]);
    }
  }
#pragma unroll
  for (int i = 0; i < 8; ++i) {
    int n = n0 + nlb * 8 + i;
    if (n >= n_nodes) continue;
    ushort4_t o;
    o[0] = f2bf(fmaxf(acc[i][0], 0.f)); o[1] = f2bf(fmaxf(acc[i][1], 0.f));
    o[2] = f2bf(fmaxf(acc[i][2], 0.f)); o[3] = f2bf(fmaxf(acc[i][3], 0.f));
    *(ushort4_t*)&h1h[(size_t)n * HID_DIM + jb * 4] = o;
  }
}

// ------- gemm2: th = bf16(h1 @ W2) (N=40 padded to 48), 64 nodes/block -------

#define G2_NODES 64
__global__ __launch_bounds__(256) void gemm2(
    const ushort* __restrict__ h1h, const float* __restrict__ W2,
    ushort* __restrict__ th, int n_nodes) {
  __shared__ float W2s[HID_DIM * 48];    // 24.6 KB
  __shared__ float insT[HID_DIM * 68];   // 34.8 KB
  int tid = threadIdx.x;
  int n0 = blockIdx.x * G2_NODES;
  for (int i = tid; i < HID_DIM * 48; i += 256) {
    int k = i / 48, j = i - k * 48;
    W2s[i] = (j < OUT_DIM) ? W2[k * OUT_DIM + j] : 0.f;
  }
  {
    int lane = tid & 63, w = tid >> 6;
    for (int nl = w; nl < G2_NODES; nl += 4) {
      int n = n0 + nl;
      float v0 = 0.f, v1 = 0.f;
      if (n < n_nodes) {
        v0 = bf2f(h1h[(size_t)n * HID_DIM + lane]);
        v1 = bf2f(h1h[(size_t)n * HID_DIM + 64 + lane]);
      }
      insT[lane * 68 + nl] = v0;
      insT[(64 + lane) * 68 + nl] = v1;
    }
  }
  __syncthreads();
  if (tid >= 192) return;
  int jb = tid % 12;    // j0 = jb*4 (jb 10,11 padding)
  int nlb = tid / 12;   // 0..15
  float acc[4][4] = {};
  const float4* WsV = (const float4*)W2s;
  const float4* inV = (const float4*)insT;
#pragma unroll 4
  for (int k = 0; k < HID_DIM; ++k) {
    float4 w = WsV[k * 12 + jb];
    float4 a = inV[k * 17 + nlb];
    float av[4] = {a.x, a.y, a.z, a.w};
#pragma unroll
    for (int i = 0; i < 4; ++i) {
      acc[i][0] = fmaf(av[i], w.x, acc[i][0]);
      acc[i][1] = fmaf(av[i], w.y, acc[i][1]);
      acc[i][2] = fmaf(av[i], w.z, acc[i][2]);
      acc[i][3] = fmaf(av[i], w.w, acc[i][3]);
    }
  }
  if (jb < 10) {
#pragma unroll
    for (int i = 0; i < 4; ++i) {
      int n = n0 + nlb * 4 + i;
      if (n >= n_nodes) continue;
      ushort4_t o;
      o[0] = f2bf(acc[i][0]); o[1] = f2bf(acc[i][1]);
      o[2] = f2bf(acc[i][2]); o[3] = f2bf(acc[i][3]);
      *(ushort4_t*)&th[(size_t)n * OUT_DIM + jb * 4] = o;
    }
  }
}

// ------- final: out = log_softmax(t[n] + sum_j t[j] + b2), one wave/node -------

__global__ __launch_bounds__(256) void final_fused(
    const ushort* __restrict__ th, const int* __restrict__ off, const int* __restrict__ esrc,
    const float* __restrict__ b2, float* __restrict__ out, int n_nodes) {
  int node = blockIdx.x * 4 + (threadIdx.x >> 6);
  int lane = threadIdx.x & 63;
  if (node >= n_nodes) return;
  // th has +64 elem pad; lanes 40..63 read garbage, masked below
  float z0 = bf2f(th[(size_t)node * OUT_DIM + lane]);
  float z1 = 0.f, z2 = 0.f, z3 = 0.f, z4 = 0.f, z5 = 0.f, z6 = 0.f, z7 = 0.f;
  int e = off[node], e1 = off[node + 1];
  for (; e + 8 <= e1; e += 8) {
    int s0 = esrc[e + 0], s1 = esrc[e + 1], s2 = esrc[e + 2], s3 = esrc[e + 3];
    int s4 = esrc[e + 4], s5 = esrc[e + 5], s6 = esrc[e + 6], s7 = esrc[e + 7];
    z0 += bf2f(th[(size_t)s0 * OUT_DIM + lane]);
    z1 += bf2f(th[(size_t)s1 * OUT_DIM + lane]);
    z2 += bf2f(th[(size_t)s2 * OUT_DIM + lane]);
    z3 += bf2f(th[(size_t)s3 * OUT_DIM + lane]);
    z4 += bf2f(th[(size_t)s4 * OUT_DIM + lane]);
    z5 += bf2f(th[(size_t)s5 * OUT_DIM + lane]);
    z6 += bf2f(th[(size_t)s6 * OUT_DIM + lane]);
    z7 += bf2f(th[(size_t)s7 * OUT_DIM + lane]);
  }
  for (; e < e1; ++e) z1 += bf2f(th[(size_t)esrc[e] * OUT_DIM + lane]);
  float z = ((z0 + z1) + (z2 + z3)) + ((z4 + z5) + (z6 + z7)) +
            ((lane < OUT_DIM) ? b2[lane] : 0.f);
  float zz = (lane < OUT_DIM) ? z : -INFINITY;
  float m = zz;
#pragma unroll
  for (int d = 32; d; d >>= 1) m = fmaxf(m, __shfl_xor(m, d, 64));
  float ev = (lane < OUT_DIM) ? expf(zz - m) : 0.f;
  float s = ev;
#pragma unroll
  for (int d = 32; d; d >>= 1) s += __shfl_xor(s, d, 64);
  if (lane < OUT_DIM) out[(size_t)node * OUT_DIM + lane] = zz - m - logf(s);
}

// ---------------- launch ----------------

extern "C" void kernel_launch(void* const* d_in, const int* in_sizes, int n_in,
                              void* d_out, int out_size, void* d_ws, size_t ws_size,
                              hipStream_t stream) {
  const float* x  = (const float*)d_in[0];
  const int*   ei = (const int*)d_in[1];    // [2][E] int32
  const float* W1 = (const float*)d_in[2];
  const float* b1 = (const float*)d_in[3];
  const float* W2 = (const float*)d_in[4];
  const float* b2 = (const float*)d_in[5];
  float* out = (float*)d_out;

  int n_nodes = in_sizes[0] / IN_DIM;
  int n_edges = in_sizes[1] / 2;
  const int* src = ei;
  const int* dst = ei + n_edges;

  char* p = (char*)d_ws;
  int* deg    = (int*)p;            p += (size_t)n_nodes * 4;
  int* off    = (int*)p;            p += (size_t)(n_nodes + 1) * 4;
  int* cursor = (int*)p;            p += (size_t)n_nodes * 4;
  int* bsums  = (int*)p;            p += 1024;
  int* esrc   = (int*)p;            p += (size_t)n_edges * 4;
  ushort* xh    = (ushort*)p;       p += (size_t)n_nodes * IN_DIM * 2;
  ushort* aggrh = (ushort*)p;       p += (size_t)n_nodes * IN_DIM * 2;
  ushort* h1h   = (ushort*)p;       p += (size_t)n_nodes * HID_DIM * 2;
  ushort* th    = (ushort*)p;       p += ((size_t)n_nodes * OUT_DIM + 64) * 2;

  hipMemsetAsync(deg, 0, (size_t)n_nodes * 4, stream);

  int n8 = n_nodes * IN_DIM / 8;
  cvt_bf16<<<(n8 + 255) / 256, 256, 0, stream>>>((const float4*)x, (ushort8_t*)xh, n8);

  int egrid = (n_edges + 255) / 256;
  count_deg<<<egrid, 256, 0, stream>>>(dst, deg, n_edges);

  int nb = (n_nodes + 1023) / 1024;
  scan1<<<nb, 256, 0, stream>>>(deg, off, bsums, n_nodes);
  scan2<<<1, 64, 0, stream>>>(bsums, nb);
  scan3<<<(n_nodes + 256) / 256, 256, 0, stream>>>(off, bsums, n_nodes, n_edges);

  hipMemcpyAsync(cursor, off, (size_t)n_nodes * 4, hipMemcpyDeviceToDevice, stream);
  int fgrid = ((n_edges + 1) / 2 + 255) / 256;
  fill_csr<<<fgrid, 256, 0, stream>>>(src, dst, cursor, esrc, n_edges);

  agg1<<<(n_nodes + 3) / 4, 256, 0, stream>>>(xh, off, esrc, aggrh, n_nodes);
  gemm1_relu<<<(n_nodes + G1_NODES - 1) / G1_NODES, 256, 0, stream>>>(
      aggrh, W1, b1, h1h, n_nodes);
  gemm2<<<(n_nodes + G2_NODES - 1) / G2_NODES, 256, 0, stream>>>(h1h, W2, th, n_nodes);
  final_fused<<<(n_nodes + 3) / 4, 256, 0, stream>>>(th, off, esrc, b2, out, n_nodes);
}

// Round 5
// 298.299 us; speedup vs baseline: 8.5698x; 1.4617x over previous
//
#include <hip/hip_runtime.h>
#include <math.h>

// GIN 2-layer, round 5: LDS-binned counting-sort CSR build (no per-node global
// atomics, coalesced edge writes), bf16 gathered intermediates, reg-tiled GEMMs.

#define IN_DIM 64
#define HID_DIM 128
#define OUT_DIM 40

#define BSH 8          // 256 nodes per bucket
#define MAXNB 512      // supports n_nodes <= 131072 (also the 17-bit pack limit)
#define EPB 4096       // edges per block in count/scatter

typedef unsigned short ushort;
typedef ushort ushort4_t __attribute__((ext_vector_type(4)));
typedef ushort ushort8_t __attribute__((ext_vector_type(8)));

__device__ __forceinline__ ushort f2bf(float f) {
  unsigned u = __float_as_uint(f);
  u += 0x7fffu + ((u >> 16) & 1u);
  return (ushort)(u >> 16);
}
__device__ __forceinline__ float bf2f(ushort h) {
  return __uint_as_float(((unsigned)h) << 16);
}

// ---------------- fp32 -> bf16 bulk convert ----------------

__global__ __launch_bounds__(256) void cvt_bf16(const float4* __restrict__ in,
                                                ushort8_t* __restrict__ out, int n8) {
  int i = blockIdx.x * 256 + threadIdx.x;
  if (i >= n8) return;
  float4 a = in[2 * i], b = in[2 * i + 1];
  ushort8_t o;
  o[0] = f2bf(a.x); o[1] = f2bf(a.y); o[2] = f2bf(a.z); o[3] = f2bf(a.w);
  o[4] = f2bf(b.x); o[5] = f2bf(b.y); o[6] = f2bf(b.z); o[7] = f2bf(b.w);
  out[i] = o;
}

// ---------------- binned CSR build ----------------

__global__ __launch_bounds__(256) void bucket_count(const int* __restrict__ dst,
                                                    int* __restrict__ bcnt,
                                                    int n_edges, int nb) {
  __shared__ int hist[MAXNB];
  int tid = threadIdx.x;
  for (int i = tid; i < nb; i += 256) hist[i] = 0;
  __syncthreads();
  int e0 = blockIdx.x * EPB;
  int end = min(e0 + EPB, n_edges);
  for (int i = e0 + tid; i < end; i += 256) atomicAdd(&hist[dst[i] >> BSH], 1);
  __syncthreads();
  for (int i = tid; i < nb; i += 256)
    if (hist[i]) atomicAdd(&bcnt[i], hist[i]);
}

__global__ void bucket_scan(const int* __restrict__ bcnt, int* __restrict__ bbase,
                            int* __restrict__ gcur, int nb, int n_edges) {
  int lane = threadIdx.x;  // 64 threads
  int carry = 0;
  for (int c = 0; c < nb; c += 64) {
    int v = (c + lane < nb) ? bcnt[c + lane] : 0;
    int incl = v;
#pragma unroll
    for (int d = 1; d < 64; d <<= 1) {
      int t = __shfl_up(incl, d, 64);
      if (lane >= d) incl += t;
    }
    if (c + lane < nb) {
      int excl = carry + incl - v;
      bbase[c + lane] = excl;
      gcur[c + lane] = excl;
    }
    carry += __shfl(incl, 63, 64);
  }
  if (lane == 0) bbase[nb] = n_edges;
}

__global__ __launch_bounds__(256) void bucket_scatter(
    const int* __restrict__ src, const int* __restrict__ dst,
    int* __restrict__ gcur, int* __restrict__ epk, int n_edges, int nb) {
  __shared__ int hist[MAXNB];
  __shared__ int lexcl[MAXNB];
  __shared__ int lofs[MAXNB];
  __shared__ int gbase[MAXNB];
  __shared__ int spk[EPB];
  __shared__ ushort sbid[EPB];
  int tid = threadIdx.x;
  for (int i = tid; i < nb; i += 256) { hist[i] = 0; lofs[i] = 0; }
  __syncthreads();
  int e0 = blockIdx.x * EPB;
  int cnt = min(EPB, n_edges - e0);
  for (int i = tid; i < cnt; i += 256) atomicAdd(&hist[dst[e0 + i] >> BSH], 1);
  __syncthreads();
  if (tid < 64) {  // wave-0 scan of nb entries
    int carry = 0;
    for (int c = 0; c < nb; c += 64) {
      int v = (c + tid < nb) ? hist[c + tid] : 0;
      int incl = v;
#pragma unroll
      for (int d = 1; d < 64; d <<= 1) {
        int t = __shfl_up(incl, d, 64);
        if (tid >= d) incl += t;
      }
      if (c + tid < nb) lexcl[c + tid] = carry + incl - v;
      carry += __shfl(incl, 63, 64);
    }
  }
  __syncthreads();
  for (int i = tid; i < nb; i += 256)
    if (hist[i]) gbase[i] = atomicAdd(&gcur[i], hist[i]);
  __syncthreads();
  for (int i = tid; i < cnt; i += 256) {
    int d = dst[e0 + i], s = src[e0 + i];
    int b = d >> BSH;
    int p = lexcl[b] + atomicAdd(&lofs[b], 1);
    spk[p] = ((d & 255) << 17) | s;      // n_nodes < 2^17
    sbid[p] = (ushort)b;
  }
  __syncthreads();
  for (int i = tid; i < cnt; i += 256) {  // coalesced copy-out
    int b = sbid[i];
    epk[gbase[b] + (i - lexcl[b])] = spk[i];
  }
}

__global__ __launch_bounds__(256) void bucket_csr(
    const int* __restrict__ epk, const int* __restrict__ bbase,
    int* __restrict__ off, int* __restrict__ esrc, int n_nodes, int n_edges) {
  __shared__ int hist[256];
  __shared__ int cur[256];
  int b = blockIdx.x;
  int nb0 = b << BSH;
  int nn = min(256, n_nodes - nb0);
  int e0 = bbase[b], e1 = bbase[b + 1];
  int tid = threadIdx.x;
  hist[tid] = 0;
  __syncthreads();
  for (int i = e0 + tid; i < e1; i += 256) atomicAdd(&hist[epk[i] >> 17], 1);
  __syncthreads();
  if (tid < 64) {  // scan 256 entries
    int carry = 0;
#pragma unroll
    for (int c = 0; c < 256; c += 64) {
      int v = hist[c + tid];
      int incl = v;
#pragma unroll
      for (int d = 1; d < 64; d <<= 1) {
        int t = __shfl_up(incl, d, 64);
        if (tid >= d) incl += t;
      }
      cur[c + tid] = carry + incl - v;
      carry += __shfl(incl, 63, 64);
    }
  }
  __syncthreads();
  if (tid < nn) off[nb0 + tid] = e0 + cur[tid];
  if (b == gridDim.x - 1 && tid == 0) off[n_nodes] = n_edges;
  __syncthreads();  // off reads cur before scatter mutates it
  for (int i = e0 + tid; i < e1; i += 256) {
    int p = epk[i];
    int pos = atomicAdd(&cur[p >> 17], 1);
    esrc[e0 + pos] = p & 0x1FFFF;
  }
}

// -------- agg1: aggr1h[n] = bf16(x[n] + sum_j x[j]) --------

__global__ __launch_bounds__(256) void agg1(
    const ushort* __restrict__ xh, const int* __restrict__ off, const int* __restrict__ esrc,
    ushort* __restrict__ aggrh, int n_nodes) {
  int node = blockIdx.x * 4 + (threadIdx.x >> 6);
  int lane = threadIdx.x & 63;
  if (node >= n_nodes) return;
  float a0 = bf2f(xh[(size_t)node * IN_DIM + lane]);
  float a1 = 0.f, a2 = 0.f, a3 = 0.f, a4 = 0.f, a5 = 0.f, a6 = 0.f, a7 = 0.f;
  int e = off[node], e1 = off[node + 1];
  for (; e + 8 <= e1; e += 8) {
    int s0 = esrc[e + 0], s1 = esrc[e + 1], s2 = esrc[e + 2], s3 = esrc[e + 3];
    int s4 = esrc[e + 4], s5 = esrc[e + 5], s6 = esrc[e + 6], s7 = esrc[e + 7];
    a0 += bf2f(xh[(size_t)s0 * IN_DIM + lane]);
    a1 += bf2f(xh[(size_t)s1 * IN_DIM + lane]);
    a2 += bf2f(xh[(size_t)s2 * IN_DIM + lane]);
    a3 += bf2f(xh[(size_t)s3 * IN_DIM + lane]);
    a4 += bf2f(xh[(size_t)s4 * IN_DIM + lane]);
    a5 += bf2f(xh[(size_t)s5 * IN_DIM + lane]);
    a6 += bf2f(xh[(size_t)s6 * IN_DIM + lane]);
    a7 += bf2f(xh[(size_t)s7 * IN_DIM + lane]);
  }
  for (; e < e1; ++e) a1 += bf2f(xh[(size_t)esrc[e] * IN_DIM + lane]);
  float s = ((a0 + a1) + (a2 + a3)) + ((a4 + a5) + (a6 + a7));
  aggrh[(size_t)node * IN_DIM + lane] = f2bf(s);
}

// ------- gemm1: h1h = bf16(relu(aggr1 @ W1 + b1)), 64 nodes/block -------

#define G1_NODES 64
__global__ __launch_bounds__(256) void gemm1_relu(
    const ushort* __restrict__ aggrh, const float* __restrict__ W1,
    const float* __restrict__ b1, ushort* __restrict__ h1h, int n_nodes) {
  __shared__ float Ws[IN_DIM * HID_DIM];
  __shared__ float insT[IN_DIM * 68];
  int tid = threadIdx.x;
  int n0 = blockIdx.x * G1_NODES;
  for (int i = tid; i < IN_DIM * HID_DIM; i += 256) Ws[i] = W1[i];
  {
    int lane = tid & 63, w = tid >> 6;
    for (int nl = w; nl < G1_NODES; nl += 4) {
      int n = n0 + nl;
      insT[lane * 68 + nl] = (n < n_nodes) ? bf2f(aggrh[(size_t)n * IN_DIM + lane]) : 0.f;
    }
  }
  __syncthreads();
  int jb = tid & 31;
  int nlb = tid >> 5;
  float4 bias = ((const float4*)b1)[jb];
  float acc[8][4];
#pragma unroll
  for (int i = 0; i < 8; ++i) {
    acc[i][0] = bias.x; acc[i][1] = bias.y; acc[i][2] = bias.z; acc[i][3] = bias.w;
  }
  const float4* WsV = (const float4*)Ws;
  const float4* inV = (const float4*)insT;
#pragma unroll 4
  for (int k = 0; k < IN_DIM; ++k) {
    float4 w = WsV[k * 32 + jb];
    float4 aA = inV[k * 17 + nlb * 2 + 0];
    float4 aB = inV[k * 17 + nlb * 2 + 1];
    float av[8] = {aA.x, aA.y, aA.z, aA.w, aB.x, aB.y, aB.z, aB.w};
#pragma unroll
    for (int i = 0; i < 8; ++i) {
      acc[i][0] = fmaf(av[i], w.x, acc[i][0]);
      acc[i][1] = fmaf(av[i], w.y, acc[i][1]);
      acc[i][2] = fmaf(av[i], w.z, acc[i][2]);
      acc[i][3] = fmaf(av[i], w.w, acc[i][3]);
    }
  }
#pragma unroll
  for (int i = 0; i < 8; ++i) {
    int n = n0 + nlb * 8 + i;
    if (n >= n_nodes) continue;
    ushort4_t o;
    o[0] = f2bf(fmaxf(acc[i][0], 0.f)); o[1] = f2bf(fmaxf(acc[i][1], 0.f));
    o[2] = f2bf(fmaxf(acc[i][2], 0.f)); o[3] = f2bf(fmaxf(acc[i][3], 0.f));
    *(ushort4_t*)&h1h[(size_t)n * HID_DIM + jb * 4] = o;
  }
}

// ------- gemm2: th = bf16(h1 @ W2), 64 nodes/block -------

#define G2_NODES 64
__global__ __launch_bounds__(256) void gemm2(
    const ushort* __restrict__ h1h, const float* __restrict__ W2,
    ushort* __restrict__ th, int n_nodes) {
  __shared__ float W2s[HID_DIM * 48];
  __shared__ float insT[HID_DIM * 68];
  int tid = threadIdx.x;
  int n0 = blockIdx.x * G2_NODES;
  for (int i = tid; i < HID_DIM * 48; i += 256) {
    int k = i / 48, j = i - k * 48;
    W2s[i] = (j < OUT_DIM) ? W2[k * OUT_DIM + j] : 0.f;
  }
  {
    int lane = tid & 63, w = tid >> 6;
    for (int nl = w; nl < G2_NODES; nl += 4) {
      int n = n0 + nl;
      float v0 = 0.f, v1 = 0.f;
      if (n < n_nodes) {
        v0 = bf2f(h1h[(size_t)n * HID_DIM + lane]);
        v1 = bf2f(h1h[(size_t)n * HID_DIM + 64 + lane]);
      }
      insT[lane * 68 + nl] = v0;
      insT[(64 + lane) * 68 + nl] = v1;
    }
  }
  __syncthreads();
  if (tid >= 192) return;
  int jb = tid % 12;
  int nlb = tid / 12;
  float acc[4][4] = {};
  const float4* WsV = (const float4*)W2s;
  const float4* inV = (const float4*)insT;
#pragma unroll 4
  for (int k = 0; k < HID_DIM; ++k) {
    float4 w = WsV[k * 12 + jb];
    float4 a = inV[k * 17 + nlb];
    float av[4] = {a.x, a.y, a.z, a.w};
#pragma unroll
    for (int i = 0; i < 4; ++i) {
      acc[i][0] = fmaf(av[i], w.x, acc[i][0]);
      acc[i][1] = fmaf(av[i], w.y, acc[i][1]);
      acc[i][2] = fmaf(av[i], w.z, acc[i][2]);
      acc[i][3] = fmaf(av[i], w.w, acc[i][3]);
    }
  }
  if (jb < 10) {
#pragma unroll
    for (int i = 0; i < 4; ++i) {
      int n = n0 + nlb * 4 + i;
      if (n >= n_nodes) continue;
      ushort4_t o;
      o[0] = f2bf(acc[i][0]); o[1] = f2bf(acc[i][1]);
      o[2] = f2bf(acc[i][2]); o[3] = f2bf(acc[i][3]);
      *(ushort4_t*)&th[(size_t)n * OUT_DIM + jb * 4] = o;
    }
  }
}

// ------- final: out = log_softmax(t[n] + sum_j t[j] + b2) -------

__global__ __launch_bounds__(256) void final_fused(
    const ushort* __restrict__ th, const int* __restrict__ off, const int* __restrict__ esrc,
    const float* __restrict__ b2, float* __restrict__ out, int n_nodes) {
  int node = blockIdx.x * 4 + (threadIdx.x >> 6);
  int lane = threadIdx.x & 63;
  if (node >= n_nodes) return;
  float z0 = bf2f(th[(size_t)node * OUT_DIM + lane]);
  float z1 = 0.f, z2 = 0.f, z3 = 0.f, z4 = 0.f, z5 = 0.f, z6 = 0.f, z7 = 0.f;
  int e = off[node], e1 = off[node + 1];
  for (; e + 8 <= e1; e += 8) {
    int s0 = esrc[e + 0], s1 = esrc[e + 1], s2 = esrc[e + 2], s3 = esrc[e + 3];
    int s4 = esrc[e + 4], s5 = esrc[e + 5], s6 = esrc[e + 6], s7 = esrc[e + 7];
    z0 += bf2f(th[(size_t)s0 * OUT_DIM + lane]);
    z1 += bf2f(th[(size_t)s1 * OUT_DIM + lane]);
    z2 += bf2f(th[(size_t)s2 * OUT_DIM + lane]);
    z3 += bf2f(th[(size_t)s3 * OUT_DIM + lane]);
    z4 += bf2f(th[(size_t)s4 * OUT_DIM + lane]);
    z5 += bf2f(th[(size_t)s5 * OUT_DIM + lane]);
    z6 += bf2f(th[(size_t)s6 * OUT_DIM + lane]);
    z7 += bf2f(th[(size_t)s7 * OUT_DIM + lane]);
  }
  for (; e < e1; ++e) z1 += bf2f(th[(size_t)esrc[e] * OUT_DIM + lane]);
  float z = ((z0 + z1) + (z2 + z3)) + ((z4 + z5) + (z6 + z7)) +
            ((lane < OUT_DIM) ? b2[lane] : 0.f);
  float zz = (lane < OUT_DIM) ? z : -INFINITY;
  float m = zz;
#pragma unroll
  for (int d = 32; d; d >>= 1) m = fmaxf(m, __shfl_xor(m, d, 64));
  float ev = (lane < OUT_DIM) ? expf(zz - m) : 0.f;
  float s = ev;
#pragma unroll
  for (int d = 32; d; d >>= 1) s += __shfl_xor(s, d, 64);
  if (lane < OUT_DIM) out[(size_t)node * OUT_DIM + lane] = zz - m - logf(s);
}

// ---------------- launch ----------------

static inline char* align256(char* p) {
  return (char*)(((uintptr_t)p + 255) & ~(uintptr_t)255);
}

extern "C" void kernel_launch(void* const* d_in, const int* in_sizes, int n_in,
                              void* d_out, int out_size, void* d_ws, size_t ws_size,
                              hipStream_t stream) {
  const float* x  = (const float*)d_in[0];
  const int*   ei = (const int*)d_in[1];    // [2][E] int32
  const float* W1 = (const float*)d_in[2];
  const float* b1 = (const float*)d_in[3];
  const float* W2 = (const float*)d_in[4];
  const float* b2 = (const float*)d_in[5];
  float* out = (float*)d_out;

  int n_nodes = in_sizes[0] / IN_DIM;
  int n_edges = in_sizes[1] / 2;
  const int* src = ei;
  const int* dst = ei + n_edges;
  int nb = (n_nodes + 255) >> BSH;

  char* p = (char*)d_ws;
  int* bcnt  = (int*)p;             p += MAXNB * 4;
  int* bbase = (int*)p;             p += (MAXNB + 1) * 4;
  int* gcur  = (int*)p;             p += MAXNB * 4;
  int* off   = (int*)p;             p += (size_t)(n_nodes + 1) * 4;
  p = align256(p);
  int* epk   = (int*)p;             p += (size_t)n_edges * 4;
  int* esrc  = (int*)p;             p += (size_t)n_edges * 4;
  p = align256(p);
  ushort* xh    = (ushort*)p;       p += (size_t)n_nodes * IN_DIM * 2;
  p = align256(p);
  ushort* aggrh = (ushort*)p;       p += (size_t)n_nodes * IN_DIM * 2;
  p = align256(p);
  ushort* h1h   = (ushort*)p;       p += (size_t)n_nodes * HID_DIM * 2;
  p = align256(p);
  ushort* th    = (ushort*)p;       p += ((size_t)n_nodes * OUT_DIM + 64) * 2;

  hipMemsetAsync(bcnt, 0, MAXNB * 4, stream);

  int n8 = n_nodes * IN_DIM / 8;
  cvt_bf16<<<(n8 + 255) / 256, 256, 0, stream>>>((const float4*)x, (ushort8_t*)xh, n8);

  int egrid = (n_edges + EPB - 1) / EPB;
  bucket_count<<<egrid, 256, 0, stream>>>(dst, bcnt, n_edges, nb);
  bucket_scan<<<1, 64, 0, stream>>>(bcnt, bbase, gcur, nb, n_edges);
  bucket_scatter<<<egrid, 256, 0, stream>>>(src, dst, gcur, epk, n_edges, nb);
  bucket_csr<<<nb, 256, 0, stream>>>(epk, bbase, off, esrc, n_nodes, n_edges);

  agg1<<<(n_nodes + 3) / 4, 256, 0, stream>>>(xh, off, esrc, aggrh, n_nodes);
  gemm1_relu<<<(n_nodes + G1_NODES - 1) / G1_NODES, 256, 0, stream>>>(
      aggrh, W1, b1, h1h, n_nodes);
  gemm2<<<(n_nodes + G2_NODES - 1) / G2_NODES, 256, 0, stream>>>(h1h, W2, th, n_nodes);
  final_fused<<<(n_nodes + 3) / 4, 256, 0, stream>>>(th, off, esrc, b2, out, n_nodes);
}